// Round 13
// baseline (971.032 us; speedup 1.0000x reference)
//
#include <hip/hip_runtime.h>
#include <math.h>

#define V_WORDS 20000
#define MM 32
#define EE 128
#define HH 4
#define DHH 32
#define NN 8192
#define LL 64
#define CC 128

typedef short bf16x8 __attribute__((ext_vector_type(8)));
typedef float f32x4 __attribute__((ext_vector_type(4)));
typedef unsigned short u16;
typedef unsigned int u32;

__device__ __forceinline__ u16 f2bf(float x) {
    u32 u = __float_as_uint(x);
    u32 r = (u + 0x7FFFu + ((u >> 16) & 1u)) >> 16;
    return (u16)r;
}
__device__ __forceinline__ float bflo(u32 u) { return __uint_as_float(u << 16); }
__device__ __forceinline__ float bfhi(u32 u) { return __uint_as_float(u & 0xFFFF0000u); }

// ---------------------------------------------------------------------------
// Kernel 0: pack conv weights into bf16 MFMA B-fragment order (unchanged).
// ---------------------------------------------------------------------------
__global__ __launch_bounds__(256)
void pack_weights(const float* __restrict__ w3,
                  const float* __restrict__ w4,
                  const float* __restrict__ w5,
                  u16* __restrict__ Bpack)
{
    const int s = blockIdx.x;
    const int t = threadIdx.x;
    const int lane = t & 63;

    const float* src;
    int K, sl;
    if (s < 12)      { src = w3; K = 3; sl = s; }
    else if (s < 28) { src = w4; K = 4; sl = s - 12; }
    else             { src = w5; K = 5; sl = s - 28; }
    const int j  = sl >> 2;
    const int e0 = (sl & 3) * 32;

    for (int nt = (t >> 6); nt < 8; nt += 4) {
        const int c = nt * 16 + (lane & 15);
        const int kb = (lane >> 4) * 8;
        u16 vals[8];
        #pragma unroll
        for (int i = 0; i < 8; ++i) {
            const int e = e0 + kb + i;
            vals[i] = f2bf(src[(c * EE + e) * K + j]);
        }
        u16* dst = Bpack + (((size_t)s * 8 + nt) * 64 + lane) * 8;
        *(bf16x8*)dst = *(const bf16x8*)vals;
    }
}

// ---------------------------------------------------------------------------
// Kernel A: Kn/Vn projections over the 8192 distinct news rows (unchanged).
// ---------------------------------------------------------------------------
__global__ __launch_bounds__(256)
void kv_proj_kernel(const float* __restrict__ table,
                    const float* __restrict__ in_w,
                    const float* __restrict__ in_b,
                    u16* __restrict__ Kn16, u16* __restrict__ Vn16)
{
    const int n0 = blockIdx.x * 8;
    const int t = threadIdx.x;
    __shared__ float tbl[8][EE];
    {
        const int r = t >> 5, q4 = (t & 31) * 4;
        *(float4*)&tbl[r][q4] = *(const float4*)&table[(size_t)(n0 + r) * EE + q4];
    }
    __syncthreads();

    const int sel = t >> 7;
    const int i = t & 127;
    const float* w = in_w + (size_t)(sel + 1) * EE * EE + (size_t)i * EE;
    const float bias = in_b[(sel + 1) * EE + i];

    float acc[8];
    #pragma unroll
    for (int r = 0; r < 8; ++r) acc[r] = bias;
    for (int k = 0; k < EE; k += 4) {
        const float4 wv = *(const float4*)&w[k];
        #pragma unroll
        for (int r = 0; r < 8; ++r) {
            acc[r] += tbl[r][k]     * wv.x + tbl[r][k + 1] * wv.y
                    + tbl[r][k + 2] * wv.z + tbl[r][k + 3] * wv.w;
        }
    }
    u16* dst = sel ? Vn16 : Kn16;
    #pragma unroll
    for (int r = 0; r < 8; ++r) dst[(size_t)(n0 + r) * EE + i] = f2bf(acc[r]);
}

// ---------------------------------------------------------------------------
// Kernel B: per-word attention (unchanged from R11 — demand-bounded via
// unroll pragmas, plain (256); ~137 us, no spill).
// ---------------------------------------------------------------------------
#define WPB 8
__global__ __launch_bounds__(256)
void word_attn_kernel(const int* __restrict__ word2news,
                      const int* __restrict__ word2news_len,
                      const float* __restrict__ table,
                      const float* __restrict__ in_w,
                      const float* __restrict__ in_b,
                      const float* __restrict__ out_w,
                      const float* __restrict__ out_b,
                      const u16* __restrict__ Kn16,
                      const u16* __restrict__ Vn16,
                      u16* __restrict__ we16)
{
    const int v0 = blockIdx.x * WPB;
    const int t = threadIdx.x;

    __shared__ int   rows[WPB][MM];
    __shared__ int   lenS[WPB];
    __shared__ float q[WPB][EE];
    __shared__ float qh[WPB][EE];
    __shared__ float attn[WPB][HH][MM];
    __shared__ float osh[WPB][EE];

    {
        const int w = t >> 5, m = t & 31;
        rows[w][m] = word2news[(size_t)(v0 + w) * MM + m];
        if (t < WPB) lenS[t] = word2news_len[v0 + t];
    }
    __syncthreads();

    // q = masked mean of table rows (fixed trip, 4-deep pipelined loads)
    {
        const int w = t >> 5, d0 = (t & 31) * 4;
        const int L = lenS[w];
        float4 a = {0.f, 0.f, 0.f, 0.f};
        #pragma unroll 4
        for (int m = 0; m < MM; ++m) {
            const float4 x = *(const float4*)&table[(size_t)rows[w][m] * EE + d0];
            if (m < L) { a.x += x.x; a.y += x.y; a.z += x.z; a.w += x.w; }
        }
        const float inv = (L > 0) ? 1.0f / (float)L : 0.0f;
        a.x *= inv; a.y *= inv; a.z *= inv; a.w *= inv;
        *(float4*)&q[w][d0] = a;
    }
    __syncthreads();

    // qh = q @ wq^T + bq  (bounded 4-deep weight-load window)
    {
        const int g = t >> 7, i = t & 127;
        const float* wr = in_w + (size_t)i * EE;
        float acc[4] = {0.f, 0.f, 0.f, 0.f};
        #pragma unroll 4
        for (int k = 0; k < EE; k += 4) {
            const float4 wv = *(const float4*)&wr[k];
            #pragma unroll
            for (int w4 = 0; w4 < 4; ++w4) {
                const float* qw = q[g * 4 + w4];
                acc[w4] += qw[k] * wv.x + qw[k + 1] * wv.y
                         + qw[k + 2] * wv.z + qw[k + 3] * wv.w;
            }
        }
        const float b = in_b[i];
        #pragma unroll
        for (int w4 = 0; w4 < 4; ++w4) qh[g * 4 + w4][i] = acc[w4] + b;
    }
    __syncthreads();

    // scores (gather Kn rows) + softmax over m; one head at a time so only
    // 4 uint4 of the Kn row are in flight (not the hoisted 16).
    {
        const int w = t >> 5, m = t & 31;
        const int L = lenS[w];
        float s[HH] = {-1e9f, -1e9f, -1e9f, -1e9f};
        if (m < L) {
            const uint4* kr = (const uint4*)(Kn16 + (size_t)rows[w][m] * EE);
            #pragma unroll 1
            for (int h = 0; h < HH; ++h) {
                float a = 0.f;
                #pragma unroll
                for (int k8 = 0; k8 < 4; ++k8) {
                    const uint4 u = kr[h * 4 + k8];
                    const float4 q0 = *(const float4*)&qh[w][h * 32 + k8 * 8];
                    const float4 q1 = *(const float4*)&qh[w][h * 32 + k8 * 8 + 4];
                    a += q0.x * bflo(u.x) + q0.y * bfhi(u.x)
                       + q0.z * bflo(u.y) + q0.w * bfhi(u.y)
                       + q1.x * bflo(u.z) + q1.y * bfhi(u.z)
                       + q1.z * bflo(u.w) + q1.w * bfhi(u.w);
                }
                s[h] = a * 0.17677669529663687f;
            }
        }
        #pragma unroll
        for (int h = 0; h < HH; ++h) {
            float mx = s[h];
            #pragma unroll
            for (int off = 16; off > 0; off >>= 1)
                mx = fmaxf(mx, __shfl_xor(mx, off, 32));
            const float ex = expf(s[h] - mx);      // masked lanes underflow to 0
            float sum = ex;
            #pragma unroll
            for (int off = 16; off > 0; off >>= 1)
                sum += __shfl_xor(sum, off, 32);
            attn[w][h][m] = ex / sum;
        }
    }
    __syncthreads();

    // o = attn-weighted sum of Vn rows (fixed trip; attn==0 for m>=len)
    {
        const int w = t >> 5, d0 = (t & 31) * 4;
        const int h = d0 >> 5;
        float4 a = {0.f, 0.f, 0.f, 0.f};
        #pragma unroll 4
        for (int m = 0; m < MM; ++m) {
            const float aw = attn[w][h][m];
            const u32* vr = (const u32*)(Vn16 + (size_t)rows[w][m] * EE + d0);
            const u32 u0 = vr[0], u1 = vr[1];
            a.x += aw * bflo(u0); a.y += aw * bfhi(u0);
            a.z += aw * bflo(u1); a.w += aw * bfhi(u1);
        }
        *(float4*)&osh[w][d0] = a;
    }
    __syncthreads();

    // out proj + bf16 store (bounded 4-deep weight-load window)
    {
        const int g = t >> 7, i = t & 127;
        const float* wr = out_w + (size_t)i * EE;
        float acc[4] = {0.f, 0.f, 0.f, 0.f};
        #pragma unroll 4
        for (int k = 0; k < EE; k += 4) {
            const float4 wv = *(const float4*)&wr[k];
            #pragma unroll
            for (int w4 = 0; w4 < 4; ++w4) {
                const float* ow = osh[g * 4 + w4];
                acc[w4] += ow[k] * wv.x + ow[k + 1] * wv.y
                         + ow[k + 2] * wv.z + ow[k + 3] * wv.w;
            }
        }
        const float b = out_b[i];
        #pragma unroll
        for (int w4 = 0; w4 < 4; ++w4) {
            const int w = g * 4 + w4;
            we16[(size_t)(v0 + w) * EE + i] =
                (lenS[w] > 0) ? f2bf(acc[w4] + b) : (u16)0;
        }
    }
}

// ---------------------------------------------------------------------------
// Kernel 2: implicit-GEMM conv, 2 news per block.
// REGISTER DISCIPLINE (R4-R12): unroll depth controls in-flight operand
// demand; cap must be >= demand. Measured: unroll 2 -> 64 arch + 64 AGPR.
// R13: unroll 3 -> demand ~160 unified; (256,3) caps at 170 >= 160.
// Each 3-slice body amortizes its exposed L2 B-load latency over ~930 cyc of
// MFMA (vs 620 at unroll 2). GUARDRAIL: WRITE_SIZE > 50 MB => spill, revert.
// Doc gather now uint4 (row pad is exactly 1 uint4: 136 u16 = 17 uint4),
// 8 coalesced 16B loads/thread instead of 32 u32 loads.
// ---------------------------------------------------------------------------
#define DSTRIDE 136              // u16 per doc row (16B-aligned, 68 words)
#define DOCSZ   (68 * DSTRIDE)   // u16 per doc (64 data rows + 4 zero rows)

template<int NSL, int SBASE, int NP>
__device__ __forceinline__ void conv_g2(const u16* __restrict__ lds,
                                        const u16* __restrict__ Bpack,
                                        const float* __restrict__ bk,
                                        int p, int nth, int l,
                                        float (&mxout)[4])
{
    f32x4 acc[4][4];
    #pragma unroll
    for (int mt = 0; mt < 4; ++mt)
        #pragma unroll
        for (int k = 0; k < 4; ++k)
            acc[mt][k] = (f32x4){0.f, 0.f, 0.f, 0.f};

    const int lm = l & 15;
    const int g  = l >> 4;
    const u16* bbase = Bpack + ((size_t)SBASE * 8 + nth * 4) * 512 + l * 8;
    const u16* abase = lds + (size_t)p * DOCSZ;

    #pragma unroll 3
    for (int s = 0; s < NSL; ++s) {
        const int j  = s >> 2;
        const int e0 = (s & 3) * 32;

        bf16x8 b[4];
        #pragma unroll
        for (int k = 0; k < 4; ++k)
            b[k] = *(const bf16x8*)(bbase + s * 4096 + k * 512);

        const u16* arow = abase + (lm + j) * DSTRIDE + e0 + g * 8;
        bf16x8 a[4];
        #pragma unroll
        for (int mt = 0; mt < 4; ++mt)
            a[mt] = *(const bf16x8*)(arow + mt * (16 * DSTRIDE));

        #pragma unroll
        for (int mt = 0; mt < 4; ++mt)
            #pragma unroll
            for (int k = 0; k < 4; ++k)
                acc[mt][k] = __builtin_amdgcn_mfma_f32_16x16x32_bf16(a[mt], b[k], acc[mt][k], 0, 0, 0);
    }

    // epilogue: +bias, relu, masked max over positions, reduce across row-groups
    #pragma unroll
    for (int k = 0; k < 4; ++k) {
        const int c = nth * 64 + k * 16 + lm;
        const float bias = bk[c];
        float mx = 0.0f;                     // relu output >= 0
        #pragma unroll
        for (int mt = 0; mt < 4; ++mt) {
            #pragma unroll
            for (int r = 0; r < 4; ++r) {
                const int pos = 16 * mt + g * 4 + r;
                const float y = fmaxf(acc[mt][k][r] + bias, 0.0f);
                if (pos < NP) mx = fmaxf(mx, y);
            }
        }
        mx = fmaxf(mx, __shfl_xor(mx, 16));
        mx = fmaxf(mx, __shfl_xor(mx, 32));
        mxout[k] = mx;
    }
}

__global__ __launch_bounds__(256, 3)
void news_kernel(const int* __restrict__ news_words,
                 const u16* __restrict__ we16,
                 const u16* __restrict__ Bpack,
                 const float* __restrict__ b3,
                 const float* __restrict__ b4,
                 const float* __restrict__ b5,
                 const float* __restrict__ fcw, const float* __restrict__ fcb,
                 float* __restrict__ out)
{
    const int n0 = blockIdx.x * 2;
    const int t = threadIdx.x;
    const int w = t >> 6, l = t & 63;
    const int p = w >> 1, nth = w & 1;

    __shared__ u16 lds[2 * DOCSZ];           // 36,992 B; feats alias after convs
    __shared__ int rows[2 * LL];

    if (t < 2 * LL) rows[t] = news_words[(size_t)n0 * LL + t];
    __syncthreads();

    // gather 2 docs as uint4 (16B) rows + zero the 4 pad rows per doc.
    // doc row = 16 data uint4 + 1 pad uint4 (stride 17); pads never read.
    {
        const uint4* weU = (const uint4*)we16;     // 16 uint4 per doc row
        uint4* ldsU = (uint4*)lds;                 // doc stride 1156 uint4
        for (int idx = t; idx < 2048; idx += 256) {
            const int d = idx >> 10, rem = idx & 1023;
            const int row = rem >> 4, c4 = rem & 15;
            ldsU[d * 1156 + row * 17 + c4] = weU[(size_t)rows[d * 64 + row] * 16 + c4];
        }
        if (t < 128) {                             // 2 docs x 4 pad rows x 16
            const int d = t >> 6, rem = t & 63;
            const int row = 64 + (rem >> 4), c4 = rem & 15;
            ldsU[d * 1156 + row * 17 + c4] = (uint4){0u, 0u, 0u, 0u};
        }
    }
    __syncthreads();

    float m3[4], m4[4], m5[4];
    conv_g2<12,  0, 62>(lds, Bpack, b3, p, nth, l, m3);
    conv_g2<16, 12, 61>(lds, Bpack, b4, p, nth, l, m4);
    conv_g2<20, 28, 60>(lds, Bpack, b5, p, nth, l, m5);
    __syncthreads();                          // docs dead beyond this point

    float* feats = (float*)lds;               // [2][384] aliases doc buffer
    if ((l >> 4) == 0) {
        const int lm = l & 15;
        #pragma unroll
        for (int k = 0; k < 4; ++k) {
            const int c = nth * 64 + k * 16 + lm;
            feats[p * 384 +   0 + c] = m3[k];
            feats[p * 384 + 128 + c] = m4[k];
            feats[p * 384 + 256 + c] = m5[k];
        }
    }
    __syncthreads();

    // fc epilogue: threads 0..127, each output dim for both docs
    if (t < 128) {
        const float4* wr4 = (const float4*)(fcw + (size_t)t * (3 * CC));
        float a0 = fcb[t], a1 = a0;
        for (int f4 = 0; f4 < 96; ++f4) {
            const float4 wv = wr4[f4];
            const float4 x0 = *(const float4*)&feats[0 * 384 + f4 * 4];
            const float4 x1 = *(const float4*)&feats[1 * 384 + f4 * 4];
            a0 += x0.x * wv.x + x0.y * wv.y + x0.z * wv.z + x0.w * wv.w;
            a1 += x1.x * wv.x + x1.y * wv.y + x1.z * wv.z + x1.w * wv.w;
        }
        out[(size_t)(n0 + 0) * EE + t] = a0;
        out[(size_t)(n0 + 1) * EE + t] = a1;
    }
}

// ---------------------------------------------------------------------------
extern "C" void kernel_launch(void* const* d_in, const int* in_sizes, int n_in,
                              void* d_out, int out_size, void* d_ws, size_t ws_size,
                              hipStream_t stream)
{
    const int*   word2news     = (const int*)d_in[0];
    const int*   word2news_len = (const int*)d_in[1];
    const int*   news_words    = (const int*)d_in[2];
    const float* table         = (const float*)d_in[3];
    const float* in_w          = (const float*)d_in[4];
    const float* in_b          = (const float*)d_in[5];
    const float* out_w         = (const float*)d_in[6];
    const float* out_b         = (const float*)d_in[7];
    const float* w3            = (const float*)d_in[8];
    const float* b3            = (const float*)d_in[9];
    const float* w4            = (const float*)d_in[10];
    const float* b4            = (const float*)d_in[11];
    const float* w5            = (const float*)d_in[12];
    const float* b5            = (const float*)d_in[13];
    const float* fcw           = (const float*)d_in[14];
    const float* fcb           = (const float*)d_in[15];

    float* out = (float*)d_out;
    u16* base  = (u16*)d_ws;
    u16* we16  = base;                                   // 5.12 MB
    u16* Bpack = base + 2560000;                         // 0.39 MB
    u16* Kn16  = base + 2756608;                         // 2.10 MB
    u16* Vn16  = base + 3805184;                         // 2.10 MB  (total 9.71 MB)

    pack_weights<<<48, 256, 0, stream>>>(w3, w4, w5, Bpack);
    kv_proj_kernel<<<NN / 8, 256, 0, stream>>>(table, in_w, in_b, Kn16, Vn16);
    word_attn_kernel<<<V_WORDS / WPB, 256, 0, stream>>>(
        word2news, word2news_len, table, in_w, in_b, out_w, out_b,
        Kn16, Vn16, we16);
    news_kernel<<<NN / 2, 256, 0, stream>>>(
        news_words, we16, Bpack, b3, b4, b5, fcw, fcb, out);
}

// Round 14
// 456.117 us; speedup vs baseline: 2.1289x; 2.1289x over previous
//
#include <hip/hip_runtime.h>
#include <math.h>

#define V_WORDS 20000
#define MM 32
#define EE 128
#define HH 4
#define DHH 32
#define NN 8192
#define LL 64
#define CC 128

typedef short bf16x8 __attribute__((ext_vector_type(8)));
typedef float f32x4 __attribute__((ext_vector_type(4)));
typedef unsigned short u16;
typedef unsigned int u32;

__device__ __forceinline__ u16 f2bf(float x) {
    u32 u = __float_as_uint(x);
    u32 r = (u + 0x7FFFu + ((u >> 16) & 1u)) >> 16;
    return (u16)r;
}
__device__ __forceinline__ float bflo(u32 u) { return __uint_as_float(u << 16); }
__device__ __forceinline__ float bfhi(u32 u) { return __uint_as_float(u & 0xFFFF0000u); }

// ---------------------------------------------------------------------------
// Kernel 0: pack conv weights into bf16 MFMA B-fragment order (unchanged).
// ---------------------------------------------------------------------------
__global__ __launch_bounds__(256)
void pack_weights(const float* __restrict__ w3,
                  const float* __restrict__ w4,
                  const float* __restrict__ w5,
                  u16* __restrict__ Bpack)
{
    const int s = blockIdx.x;
    const int t = threadIdx.x;
    const int lane = t & 63;

    const float* src;
    int K, sl;
    if (s < 12)      { src = w3; K = 3; sl = s; }
    else if (s < 28) { src = w4; K = 4; sl = s - 12; }
    else             { src = w5; K = 5; sl = s - 28; }
    const int j  = sl >> 2;
    const int e0 = (sl & 3) * 32;

    for (int nt = (t >> 6); nt < 8; nt += 4) {
        const int c = nt * 16 + (lane & 15);
        const int kb = (lane >> 4) * 8;
        u16 vals[8];
        #pragma unroll
        for (int i = 0; i < 8; ++i) {
            const int e = e0 + kb + i;
            vals[i] = f2bf(src[(c * EE + e) * K + j]);
        }
        u16* dst = Bpack + (((size_t)s * 8 + nt) * 64 + lane) * 8;
        *(bf16x8*)dst = *(const bf16x8*)vals;
    }
}

// ---------------------------------------------------------------------------
// Kernel A: Kn/Vn projections over the 8192 distinct news rows (unchanged).
// ---------------------------------------------------------------------------
__global__ __launch_bounds__(256)
void kv_proj_kernel(const float* __restrict__ table,
                    const float* __restrict__ in_w,
                    const float* __restrict__ in_b,
                    u16* __restrict__ Kn16, u16* __restrict__ Vn16)
{
    const int n0 = blockIdx.x * 8;
    const int t = threadIdx.x;
    __shared__ float tbl[8][EE];
    {
        const int r = t >> 5, q4 = (t & 31) * 4;
        *(float4*)&tbl[r][q4] = *(const float4*)&table[(size_t)(n0 + r) * EE + q4];
    }
    __syncthreads();

    const int sel = t >> 7;
    const int i = t & 127;
    const float* w = in_w + (size_t)(sel + 1) * EE * EE + (size_t)i * EE;
    const float bias = in_b[(sel + 1) * EE + i];

    float acc[8];
    #pragma unroll
    for (int r = 0; r < 8; ++r) acc[r] = bias;
    for (int k = 0; k < EE; k += 4) {
        const float4 wv = *(const float4*)&w[k];
        #pragma unroll
        for (int r = 0; r < 8; ++r) {
            acc[r] += tbl[r][k]     * wv.x + tbl[r][k + 1] * wv.y
                    + tbl[r][k + 2] * wv.z + tbl[r][k + 3] * wv.w;
        }
    }
    u16* dst = sel ? Vn16 : Kn16;
    #pragma unroll
    for (int r = 0; r < 8; ++r) dst[(size_t)(n0 + r) * EE + i] = f2bf(acc[r]);
}

// ---------------------------------------------------------------------------
// Kernel B: per-word attention (unchanged from R11 — demand-bounded via
// unroll pragmas, plain (256); ~137 us, no spill).
// ---------------------------------------------------------------------------
#define WPB 8
__global__ __launch_bounds__(256)
void word_attn_kernel(const int* __restrict__ word2news,
                      const int* __restrict__ word2news_len,
                      const float* __restrict__ table,
                      const float* __restrict__ in_w,
                      const float* __restrict__ in_b,
                      const float* __restrict__ out_w,
                      const float* __restrict__ out_b,
                      const u16* __restrict__ Kn16,
                      const u16* __restrict__ Vn16,
                      u16* __restrict__ we16)
{
    const int v0 = blockIdx.x * WPB;
    const int t = threadIdx.x;

    __shared__ int   rows[WPB][MM];
    __shared__ int   lenS[WPB];
    __shared__ float q[WPB][EE];
    __shared__ float qh[WPB][EE];
    __shared__ float attn[WPB][HH][MM];
    __shared__ float osh[WPB][EE];

    {
        const int w = t >> 5, m = t & 31;
        rows[w][m] = word2news[(size_t)(v0 + w) * MM + m];
        if (t < WPB) lenS[t] = word2news_len[v0 + t];
    }
    __syncthreads();

    // q = masked mean of table rows (fixed trip, 4-deep pipelined loads)
    {
        const int w = t >> 5, d0 = (t & 31) * 4;
        const int L = lenS[w];
        float4 a = {0.f, 0.f, 0.f, 0.f};
        #pragma unroll 4
        for (int m = 0; m < MM; ++m) {
            const float4 x = *(const float4*)&table[(size_t)rows[w][m] * EE + d0];
            if (m < L) { a.x += x.x; a.y += x.y; a.z += x.z; a.w += x.w; }
        }
        const float inv = (L > 0) ? 1.0f / (float)L : 0.0f;
        a.x *= inv; a.y *= inv; a.z *= inv; a.w *= inv;
        *(float4*)&q[w][d0] = a;
    }
    __syncthreads();

    // qh = q @ wq^T + bq  (bounded 4-deep weight-load window)
    {
        const int g = t >> 7, i = t & 127;
        const float* wr = in_w + (size_t)i * EE;
        float acc[4] = {0.f, 0.f, 0.f, 0.f};
        #pragma unroll 4
        for (int k = 0; k < EE; k += 4) {
            const float4 wv = *(const float4*)&wr[k];
            #pragma unroll
            for (int w4 = 0; w4 < 4; ++w4) {
                const float* qw = q[g * 4 + w4];
                acc[w4] += qw[k] * wv.x + qw[k + 1] * wv.y
                         + qw[k + 2] * wv.z + qw[k + 3] * wv.w;
            }
        }
        const float b = in_b[i];
        #pragma unroll
        for (int w4 = 0; w4 < 4; ++w4) qh[g * 4 + w4][i] = acc[w4] + b;
    }
    __syncthreads();

    // scores (gather Kn rows) + softmax over m; one head at a time so only
    // 4 uint4 of the Kn row are in flight (not the hoisted 16).
    {
        const int w = t >> 5, m = t & 31;
        const int L = lenS[w];
        float s[HH] = {-1e9f, -1e9f, -1e9f, -1e9f};
        if (m < L) {
            const uint4* kr = (const uint4*)(Kn16 + (size_t)rows[w][m] * EE);
            #pragma unroll 1
            for (int h = 0; h < HH; ++h) {
                float a = 0.f;
                #pragma unroll
                for (int k8 = 0; k8 < 4; ++k8) {
                    const uint4 u = kr[h * 4 + k8];
                    const float4 q0 = *(const float4*)&qh[w][h * 32 + k8 * 8];
                    const float4 q1 = *(const float4*)&qh[w][h * 32 + k8 * 8 + 4];
                    a += q0.x * bflo(u.x) + q0.y * bfhi(u.x)
                       + q0.z * bflo(u.y) + q0.w * bfhi(u.y)
                       + q1.x * bflo(u.z) + q1.y * bfhi(u.z)
                       + q1.z * bflo(u.w) + q1.w * bfhi(u.w);
                }
                s[h] = a * 0.17677669529663687f;
            }
        }
        #pragma unroll
        for (int h = 0; h < HH; ++h) {
            float mx = s[h];
            #pragma unroll
            for (int off = 16; off > 0; off >>= 1)
                mx = fmaxf(mx, __shfl_xor(mx, off, 32));
            const float ex = expf(s[h] - mx);      // masked lanes underflow to 0
            float sum = ex;
            #pragma unroll
            for (int off = 16; off > 0; off >>= 1)
                sum += __shfl_xor(sum, off, 32);
            attn[w][h][m] = ex / sum;
        }
    }
    __syncthreads();

    // o = attn-weighted sum of Vn rows (fixed trip; attn==0 for m>=len)
    {
        const int w = t >> 5, d0 = (t & 31) * 4;
        const int h = d0 >> 5;
        float4 a = {0.f, 0.f, 0.f, 0.f};
        #pragma unroll 4
        for (int m = 0; m < MM; ++m) {
            const float aw = attn[w][h][m];
            const u32* vr = (const u32*)(Vn16 + (size_t)rows[w][m] * EE + d0);
            const u32 u0 = vr[0], u1 = vr[1];
            a.x += aw * bflo(u0); a.y += aw * bfhi(u0);
            a.z += aw * bflo(u1); a.w += aw * bfhi(u1);
        }
        *(float4*)&osh[w][d0] = a;
    }
    __syncthreads();

    // out proj + bf16 store (bounded 4-deep weight-load window)
    {
        const int g = t >> 7, i = t & 127;
        const float* wr = out_w + (size_t)i * EE;
        float acc[4] = {0.f, 0.f, 0.f, 0.f};
        #pragma unroll 4
        for (int k = 0; k < EE; k += 4) {
            const float4 wv = *(const float4*)&wr[k];
            #pragma unroll
            for (int w4 = 0; w4 < 4; ++w4) {
                const float* ow = osh[g * 4 + w4];
                acc[w4] += ow[k] * wv.x + ow[k + 1] * wv.y
                         + ow[k + 2] * wv.z + ow[k + 3] * wv.w;
            }
        }
        const float b = out_b[i];
        #pragma unroll
        for (int w4 = 0; w4 < 4; ++w4) {
            const int w = g * 4 + w4;
            we16[(size_t)(v0 + w) * EE + i] =
                (lenS[w] > 0) ? f2bf(acc[w4] + b) : (u16)0;
        }
    }
}

// ---------------------------------------------------------------------------
// Kernel 2: implicit-GEMM conv, 2 news per block.
// REGISTER DISCIPLINE — FINAL (R4-R13): at unroll depth U this K-loop's
// unified demand ~= 64 AGPR + 32U operands + ~30 addr.
//   U=2 -> 126..128: fits (256,4) cap of 128 EXACTLY; measured 64 arch +
//          64 AGPR, zero spill, 247 us (R12 optimum).
//   U=3 -> ~190 > 170 cap of (256,3): VGPR 84 + 2 GB scratch spill (R13).
//   full unroll, no cap -> 256 arch, 1 wave/SIMD (R6).
// DO NOT change unroll depth or launch bound independently.
// Doc gather: uint4 (row = 16 data uint4 + 1 pad uint4, stride 17) —
// staging-phase registers are dead before the K-loop; no demand interaction.
// ---------------------------------------------------------------------------
#define DSTRIDE 136              // u16 per doc row (16B-aligned, 68 words)
#define DOCSZ   (68 * DSTRIDE)   // u16 per doc (64 data rows + 4 zero rows)

template<int NSL, int SBASE, int NP>
__device__ __forceinline__ void conv_g2(const u16* __restrict__ lds,
                                        const u16* __restrict__ Bpack,
                                        const float* __restrict__ bk,
                                        int p, int nth, int l,
                                        float (&mxout)[4])
{
    f32x4 acc[4][4];
    #pragma unroll
    for (int mt = 0; mt < 4; ++mt)
        #pragma unroll
        for (int k = 0; k < 4; ++k)
            acc[mt][k] = (f32x4){0.f, 0.f, 0.f, 0.f};

    const int lm = l & 15;
    const int g  = l >> 4;
    const u16* bbase = Bpack + ((size_t)SBASE * 8 + nth * 4) * 512 + l * 8;
    const u16* abase = lds + (size_t)p * DOCSZ;

    #pragma unroll 2
    for (int s = 0; s < NSL; ++s) {
        const int j  = s >> 2;
        const int e0 = (s & 3) * 32;

        bf16x8 b[4];
        #pragma unroll
        for (int k = 0; k < 4; ++k)
            b[k] = *(const bf16x8*)(bbase + s * 4096 + k * 512);

        const u16* arow = abase + (lm + j) * DSTRIDE + e0 + g * 8;
        bf16x8 a[4];
        #pragma unroll
        for (int mt = 0; mt < 4; ++mt)
            a[mt] = *(const bf16x8*)(arow + mt * (16 * DSTRIDE));

        #pragma unroll
        for (int mt = 0; mt < 4; ++mt)
            #pragma unroll
            for (int k = 0; k < 4; ++k)
                acc[mt][k] = __builtin_amdgcn_mfma_f32_16x16x32_bf16(a[mt], b[k], acc[mt][k], 0, 0, 0);
    }

    // epilogue: +bias, relu, masked max over positions, reduce across row-groups
    #pragma unroll
    for (int k = 0; k < 4; ++k) {
        const int c = nth * 64 + k * 16 + lm;
        const float bias = bk[c];
        float mx = 0.0f;                     // relu output >= 0
        #pragma unroll
        for (int mt = 0; mt < 4; ++mt) {
            #pragma unroll
            for (int r = 0; r < 4; ++r) {
                const int pos = 16 * mt + g * 4 + r;
                const float y = fmaxf(acc[mt][k][r] + bias, 0.0f);
                if (pos < NP) mx = fmaxf(mx, y);
            }
        }
        mx = fmaxf(mx, __shfl_xor(mx, 16));
        mx = fmaxf(mx, __shfl_xor(mx, 32));
        mxout[k] = mx;
    }
}

__global__ __launch_bounds__(256, 4)
void news_kernel(const int* __restrict__ news_words,
                 const u16* __restrict__ we16,
                 const u16* __restrict__ Bpack,
                 const float* __restrict__ b3,
                 const float* __restrict__ b4,
                 const float* __restrict__ b5,
                 const float* __restrict__ fcw, const float* __restrict__ fcb,
                 float* __restrict__ out)
{
    const int n0 = blockIdx.x * 2;
    const int t = threadIdx.x;
    const int w = t >> 6, l = t & 63;
    const int p = w >> 1, nth = w & 1;

    __shared__ u16 lds[2 * DOCSZ];           // 36,992 B; feats alias after convs
    __shared__ int rows[2 * LL];

    if (t < 2 * LL) rows[t] = news_words[(size_t)n0 * LL + t];
    __syncthreads();

    // gather 2 docs as uint4 (16B) rows + zero the 4 pad rows per doc.
    // doc row = 16 data uint4 + 1 pad uint4 (stride 17); pads never read.
    {
        const uint4* weU = (const uint4*)we16;     // 16 uint4 per doc row
        uint4* ldsU = (uint4*)lds;                 // doc stride 1156 uint4
        for (int idx = t; idx < 2048; idx += 256) {
            const int d = idx >> 10, rem = idx & 1023;
            const int row = rem >> 4, c4 = rem & 15;
            ldsU[d * 1156 + row * 17 + c4] = weU[(size_t)rows[d * 64 + row] * 16 + c4];
        }
        if (t < 128) {                             // 2 docs x 4 pad rows x 16
            const int d = t >> 6, rem = t & 63;
            const int row = 64 + (rem >> 4), c4 = rem & 15;
            ldsU[d * 1156 + row * 17 + c4] = (uint4){0u, 0u, 0u, 0u};
        }
    }
    __syncthreads();

    float m3[4], m4[4], m5[4];
    conv_g2<12,  0, 62>(lds, Bpack, b3, p, nth, l, m3);
    conv_g2<16, 12, 61>(lds, Bpack, b4, p, nth, l, m4);
    conv_g2<20, 28, 60>(lds, Bpack, b5, p, nth, l, m5);
    __syncthreads();                          // docs dead beyond this point

    float* feats = (float*)lds;               // [2][384] aliases doc buffer
    if ((l >> 4) == 0) {
        const int lm = l & 15;
        #pragma unroll
        for (int k = 0; k < 4; ++k) {
            const int c = nth * 64 + k * 16 + lm;
            feats[p * 384 +   0 + c] = m3[k];
            feats[p * 384 + 128 + c] = m4[k];
            feats[p * 384 + 256 + c] = m5[k];
        }
    }
    __syncthreads();

    // fc epilogue: threads 0..127, each output dim for both docs
    if (t < 128) {
        const float4* wr4 = (const float4*)(fcw + (size_t)t * (3 * CC));
        float a0 = fcb[t], a1 = a0;
        for (int f4 = 0; f4 < 96; ++f4) {
            const float4 wv = wr4[f4];
            const float4 x0 = *(const float4*)&feats[0 * 384 + f4 * 4];
            const float4 x1 = *(const float4*)&feats[1 * 384 + f4 * 4];
            a0 += x0.x * wv.x + x0.y * wv.y + x0.z * wv.z + x0.w * wv.w;
            a1 += x1.x * wv.x + x1.y * wv.y + x1.z * wv.z + x1.w * wv.w;
        }
        out[(size_t)(n0 + 0) * EE + t] = a0;
        out[(size_t)(n0 + 1) * EE + t] = a1;
    }
}

// ---------------------------------------------------------------------------
extern "C" void kernel_launch(void* const* d_in, const int* in_sizes, int n_in,
                              void* d_out, int out_size, void* d_ws, size_t ws_size,
                              hipStream_t stream)
{
    const int*   word2news     = (const int*)d_in[0];
    const int*   word2news_len = (const int*)d_in[1];
    const int*   news_words    = (const int*)d_in[2];
    const float* table         = (const float*)d_in[3];
    const float* in_w          = (const float*)d_in[4];
    const float* in_b          = (const float*)d_in[5];
    const float* out_w         = (const float*)d_in[6];
    const float* out_b         = (const float*)d_in[7];
    const float* w3            = (const float*)d_in[8];
    const float* b3            = (const float*)d_in[9];
    const float* w4            = (const float*)d_in[10];
    const float* b4            = (const float*)d_in[11];
    const float* w5            = (const float*)d_in[12];
    const float* b5            = (const float*)d_in[13];
    const float* fcw           = (const float*)d_in[14];
    const float* fcb           = (const float*)d_in[15];

    float* out = (float*)d_out;
    u16* base  = (u16*)d_ws;
    u16* we16  = base;                                   // 5.12 MB
    u16* Bpack = base + 2560000;                         // 0.39 MB
    u16* Kn16  = base + 2756608;                         // 2.10 MB
    u16* Vn16  = base + 3805184;                         // 2.10 MB  (total 9.71 MB)

    pack_weights<<<48, 256, 0, stream>>>(w3, w4, w5, Bpack);
    kv_proj_kernel<<<NN / 8, 256, 0, stream>>>(table, in_w, in_b, Kn16, Vn16);
    word_attn_kernel<<<V_WORDS / WPB, 256, 0, stream>>>(
        word2news, word2news_len, table, in_w, in_b, out_w, out_b,
        Kn16, Vn16, we16);
    news_kernel<<<NN / 2, 256, 0, stream>>>(
        news_words, we16, Bpack, b3, b4, b5, fcw, fcb, out);
}

// Round 15
// 451.396 us; speedup vs baseline: 2.1512x; 1.0105x over previous
//
#include <hip/hip_runtime.h>
#include <math.h>

#define V_WORDS 20000
#define MM 32
#define EE 128
#define HH 4
#define DHH 32
#define NN 8192
#define LL 64
#define CC 128

typedef short bf16x8 __attribute__((ext_vector_type(8)));
typedef float f32x4 __attribute__((ext_vector_type(4)));
typedef unsigned short u16;
typedef unsigned int u32;

__device__ __forceinline__ u16 f2bf(float x) {
    u32 u = __float_as_uint(x);
    u32 r = (u + 0x7FFFu + ((u >> 16) & 1u)) >> 16;
    return (u16)r;
}
__device__ __forceinline__ float bflo(u32 u) { return __uint_as_float(u << 16); }
__device__ __forceinline__ float bfhi(u32 u) { return __uint_as_float(u & 0xFFFF0000u); }

// ---------------------------------------------------------------------------
// Kernel 0: pack conv weights into bf16 MFMA B-fragment order (unchanged).
// ---------------------------------------------------------------------------
__global__ __launch_bounds__(256)
void pack_weights(const float* __restrict__ w3,
                  const float* __restrict__ w4,
                  const float* __restrict__ w5,
                  u16* __restrict__ Bpack)
{
    const int s = blockIdx.x;
    const int t = threadIdx.x;
    const int lane = t & 63;

    const float* src;
    int K, sl;
    if (s < 12)      { src = w3; K = 3; sl = s; }
    else if (s < 28) { src = w4; K = 4; sl = s - 12; }
    else             { src = w5; K = 5; sl = s - 28; }
    const int j  = sl >> 2;
    const int e0 = (sl & 3) * 32;

    for (int nt = (t >> 6); nt < 8; nt += 4) {
        const int c = nt * 16 + (lane & 15);
        const int kb = (lane >> 4) * 8;
        u16 vals[8];
        #pragma unroll
        for (int i = 0; i < 8; ++i) {
            const int e = e0 + kb + i;
            vals[i] = f2bf(src[(c * EE + e) * K + j]);
        }
        u16* dst = Bpack + (((size_t)s * 8 + nt) * 64 + lane) * 8;
        *(bf16x8*)dst = *(const bf16x8*)vals;
    }
}

// ---------------------------------------------------------------------------
// Kernel A: Kn/Vn projections over the 8192 distinct news rows (unchanged).
// ---------------------------------------------------------------------------
__global__ __launch_bounds__(256)
void kv_proj_kernel(const float* __restrict__ table,
                    const float* __restrict__ in_w,
                    const float* __restrict__ in_b,
                    u16* __restrict__ Kn16, u16* __restrict__ Vn16)
{
    const int n0 = blockIdx.x * 8;
    const int t = threadIdx.x;
    __shared__ float tbl[8][EE];
    {
        const int r = t >> 5, q4 = (t & 31) * 4;
        *(float4*)&tbl[r][q4] = *(const float4*)&table[(size_t)(n0 + r) * EE + q4];
    }
    __syncthreads();

    const int sel = t >> 7;
    const int i = t & 127;
    const float* w = in_w + (size_t)(sel + 1) * EE * EE + (size_t)i * EE;
    const float bias = in_b[(sel + 1) * EE + i];

    float acc[8];
    #pragma unroll
    for (int r = 0; r < 8; ++r) acc[r] = bias;
    for (int k = 0; k < EE; k += 4) {
        const float4 wv = *(const float4*)&w[k];
        #pragma unroll
        for (int r = 0; r < 8; ++r) {
            acc[r] += tbl[r][k]     * wv.x + tbl[r][k + 1] * wv.y
                    + tbl[r][k + 2] * wv.z + tbl[r][k + 3] * wv.w;
        }
    }
    u16* dst = sel ? Vn16 : Kn16;
    #pragma unroll
    for (int r = 0; r < 8; ++r) dst[(size_t)(n0 + r) * EE + i] = f2bf(acc[r]);
}

// ---------------------------------------------------------------------------
// Kernel B: per-word attention.
// R15: add __launch_bounds__(256,3) (cap 170, no AGPRs). SAFE NOW because
// R11 bounded every loop's in-flight window (demand ~100-130 < 170); R10's
// spill at cap 128 was with UNBOUNDED loops. Cap forces >=3 waves/SIMD on
// the scattered-gather phases that dominate this kernel (LDS 17.9 KB allows
// 8 blocks/CU, not limiting). GUARDRAIL: WRITE_SIZE GB-scale => revert.
// ---------------------------------------------------------------------------
#define WPB 8
__global__ __launch_bounds__(256, 3)
void word_attn_kernel(const int* __restrict__ word2news,
                      const int* __restrict__ word2news_len,
                      const float* __restrict__ table,
                      const float* __restrict__ in_w,
                      const float* __restrict__ in_b,
                      const float* __restrict__ out_w,
                      const float* __restrict__ out_b,
                      const u16* __restrict__ Kn16,
                      const u16* __restrict__ Vn16,
                      u16* __restrict__ we16)
{
    const int v0 = blockIdx.x * WPB;
    const int t = threadIdx.x;

    __shared__ int   rows[WPB][MM];
    __shared__ int   lenS[WPB];
    __shared__ float q[WPB][EE];
    __shared__ float qh[WPB][EE];
    __shared__ float attn[WPB][HH][MM];
    __shared__ float osh[WPB][EE];

    {
        const int w = t >> 5, m = t & 31;
        rows[w][m] = word2news[(size_t)(v0 + w) * MM + m];
        if (t < WPB) lenS[t] = word2news_len[v0 + t];
    }
    __syncthreads();

    // q = masked mean of table rows (fixed trip, 4-deep pipelined loads)
    {
        const int w = t >> 5, d0 = (t & 31) * 4;
        const int L = lenS[w];
        float4 a = {0.f, 0.f, 0.f, 0.f};
        #pragma unroll 4
        for (int m = 0; m < MM; ++m) {
            const float4 x = *(const float4*)&table[(size_t)rows[w][m] * EE + d0];
            if (m < L) { a.x += x.x; a.y += x.y; a.z += x.z; a.w += x.w; }
        }
        const float inv = (L > 0) ? 1.0f / (float)L : 0.0f;
        a.x *= inv; a.y *= inv; a.z *= inv; a.w *= inv;
        *(float4*)&q[w][d0] = a;
    }
    __syncthreads();

    // qh = q @ wq^T + bq  (bounded 4-deep weight-load window)
    {
        const int g = t >> 7, i = t & 127;
        const float* wr = in_w + (size_t)i * EE;
        float acc[4] = {0.f, 0.f, 0.f, 0.f};
        #pragma unroll 4
        for (int k = 0; k < EE; k += 4) {
            const float4 wv = *(const float4*)&wr[k];
            #pragma unroll
            for (int w4 = 0; w4 < 4; ++w4) {
                const float* qw = q[g * 4 + w4];
                acc[w4] += qw[k] * wv.x + qw[k + 1] * wv.y
                         + qw[k + 2] * wv.z + qw[k + 3] * wv.w;
            }
        }
        const float b = in_b[i];
        #pragma unroll
        for (int w4 = 0; w4 < 4; ++w4) qh[g * 4 + w4][i] = acc[w4] + b;
    }
    __syncthreads();

    // scores (gather Kn rows) + softmax over m; one head at a time so only
    // 4 uint4 of the Kn row are in flight (not the hoisted 16).
    {
        const int w = t >> 5, m = t & 31;
        const int L = lenS[w];
        float s[HH] = {-1e9f, -1e9f, -1e9f, -1e9f};
        if (m < L) {
            const uint4* kr = (const uint4*)(Kn16 + (size_t)rows[w][m] * EE);
            #pragma unroll 1
            for (int h = 0; h < HH; ++h) {
                float a = 0.f;
                #pragma unroll
                for (int k8 = 0; k8 < 4; ++k8) {
                    const uint4 u = kr[h * 4 + k8];
                    const float4 q0 = *(const float4*)&qh[w][h * 32 + k8 * 8];
                    const float4 q1 = *(const float4*)&qh[w][h * 32 + k8 * 8 + 4];
                    a += q0.x * bflo(u.x) + q0.y * bfhi(u.x)
                       + q0.z * bflo(u.y) + q0.w * bfhi(u.y)
                       + q1.x * bflo(u.z) + q1.y * bfhi(u.z)
                       + q1.z * bflo(u.w) + q1.w * bfhi(u.w);
                }
                s[h] = a * 0.17677669529663687f;
            }
        }
        #pragma unroll
        for (int h = 0; h < HH; ++h) {
            float mx = s[h];
            #pragma unroll
            for (int off = 16; off > 0; off >>= 1)
                mx = fmaxf(mx, __shfl_xor(mx, off, 32));
            const float ex = expf(s[h] - mx);      // masked lanes underflow to 0
            float sum = ex;
            #pragma unroll
            for (int off = 16; off > 0; off >>= 1)
                sum += __shfl_xor(sum, off, 32);
            attn[w][h][m] = ex / sum;
        }
    }
    __syncthreads();

    // o = attn-weighted sum of Vn rows (fixed trip; attn==0 for m>=len)
    {
        const int w = t >> 5, d0 = (t & 31) * 4;
        const int h = d0 >> 5;
        float4 a = {0.f, 0.f, 0.f, 0.f};
        #pragma unroll 4
        for (int m = 0; m < MM; ++m) {
            const float aw = attn[w][h][m];
            const u32* vr = (const u32*)(Vn16 + (size_t)rows[w][m] * EE + d0);
            const u32 u0 = vr[0], u1 = vr[1];
            a.x += aw * bflo(u0); a.y += aw * bfhi(u0);
            a.z += aw * bflo(u1); a.w += aw * bfhi(u1);
        }
        *(float4*)&osh[w][d0] = a;
    }
    __syncthreads();

    // out proj + bf16 store (bounded 4-deep weight-load window)
    {
        const int g = t >> 7, i = t & 127;
        const float* wr = out_w + (size_t)i * EE;
        float acc[4] = {0.f, 0.f, 0.f, 0.f};
        #pragma unroll 4
        for (int k = 0; k < EE; k += 4) {
            const float4 wv = *(const float4*)&wr[k];
            #pragma unroll
            for (int w4 = 0; w4 < 4; ++w4) {
                const float* ow = osh[g * 4 + w4];
                acc[w4] += ow[k] * wv.x + ow[k + 1] * wv.y
                         + ow[k + 2] * wv.z + ow[k + 3] * wv.w;
            }
        }
        const float b = out_b[i];
        #pragma unroll
        for (int w4 = 0; w4 < 4; ++w4) {
            const int w = g * 4 + w4;
            we16[(size_t)(v0 + w) * EE + i] =
                (lenS[w] > 0) ? f2bf(acc[w4] + b) : (u16)0;
        }
    }
}

// ---------------------------------------------------------------------------
// Kernel 2: implicit-GEMM conv, 2 news per block (unchanged from R14 — the
// measured optimum of this structure).
// REGISTER DISCIPLINE — FINAL (R4-R13): unified demand ~= 64 AGPR + 32U + 30.
//   U=2 + (256,4): 64 arch + 64 AGPR, zero spill, 242 us.   <- THIS
//   U=3 + (256,3): demand 190 > 170 -> 2 GB spill (R13).
//   full unroll + plain: 256 arch -> 1 wave/SIMD (R6).
// DO NOT change unroll depth or launch bound independently.
// ---------------------------------------------------------------------------
#define DSTRIDE 136              // u16 per doc row (16B-aligned, 68 words)
#define DOCSZ   (68 * DSTRIDE)   // u16 per doc (64 data rows + 4 zero rows)

template<int NSL, int SBASE, int NP>
__device__ __forceinline__ void conv_g2(const u16* __restrict__ lds,
                                        const u16* __restrict__ Bpack,
                                        const float* __restrict__ bk,
                                        int p, int nth, int l,
                                        float (&mxout)[4])
{
    f32x4 acc[4][4];
    #pragma unroll
    for (int mt = 0; mt < 4; ++mt)
        #pragma unroll
        for (int k = 0; k < 4; ++k)
            acc[mt][k] = (f32x4){0.f, 0.f, 0.f, 0.f};

    const int lm = l & 15;
    const int g  = l >> 4;
    const u16* bbase = Bpack + ((size_t)SBASE * 8 + nth * 4) * 512 + l * 8;
    const u16* abase = lds + (size_t)p * DOCSZ;

    #pragma unroll 2
    for (int s = 0; s < NSL; ++s) {
        const int j  = s >> 2;
        const int e0 = (s & 3) * 32;

        bf16x8 b[4];
        #pragma unroll
        for (int k = 0; k < 4; ++k)
            b[k] = *(const bf16x8*)(bbase + s * 4096 + k * 512);

        const u16* arow = abase + (lm + j) * DSTRIDE + e0 + g * 8;
        bf16x8 a[4];
        #pragma unroll
        for (int mt = 0; mt < 4; ++mt)
            a[mt] = *(const bf16x8*)(arow + mt * (16 * DSTRIDE));

        #pragma unroll
        for (int mt = 0; mt < 4; ++mt)
            #pragma unroll
            for (int k = 0; k < 4; ++k)
                acc[mt][k] = __builtin_amdgcn_mfma_f32_16x16x32_bf16(a[mt], b[k], acc[mt][k], 0, 0, 0);
    }

    // epilogue: +bias, relu, masked max over positions, reduce across row-groups
    #pragma unroll
    for (int k = 0; k < 4; ++k) {
        const int c = nth * 64 + k * 16 + lm;
        const float bias = bk[c];
        float mx = 0.0f;                     // relu output >= 0
        #pragma unroll
        for (int mt = 0; mt < 4; ++mt) {
            #pragma unroll
            for (int r = 0; r < 4; ++r) {
                const int pos = 16 * mt + g * 4 + r;
                const float y = fmaxf(acc[mt][k][r] + bias, 0.0f);
                if (pos < NP) mx = fmaxf(mx, y);
            }
        }
        mx = fmaxf(mx, __shfl_xor(mx, 16));
        mx = fmaxf(mx, __shfl_xor(mx, 32));
        mxout[k] = mx;
    }
}

__global__ __launch_bounds__(256, 4)
void news_kernel(const int* __restrict__ news_words,
                 const u16* __restrict__ we16,
                 const u16* __restrict__ Bpack,
                 const float* __restrict__ b3,
                 const float* __restrict__ b4,
                 const float* __restrict__ b5,
                 const float* __restrict__ fcw, const float* __restrict__ fcb,
                 float* __restrict__ out)
{
    const int n0 = blockIdx.x * 2;
    const int t = threadIdx.x;
    const int w = t >> 6, l = t & 63;
    const int p = w >> 1, nth = w & 1;

    __shared__ u16 lds[2 * DOCSZ];           // 36,992 B; feats alias after convs
    __shared__ int rows[2 * LL];

    if (t < 2 * LL) rows[t] = news_words[(size_t)n0 * LL + t];
    __syncthreads();

    // gather 2 docs as uint4 (16B) rows + zero the 4 pad rows per doc.
    // doc row = 16 data uint4 + 1 pad uint4 (stride 17); pads never read.
    {
        const uint4* weU = (const uint4*)we16;     // 16 uint4 per doc row
        uint4* ldsU = (uint4*)lds;                 // doc stride 1156 uint4
        for (int idx = t; idx < 2048; idx += 256) {
            const int d = idx >> 10, rem = idx & 1023;
            const int row = rem >> 4, c4 = rem & 15;
            ldsU[d * 1156 + row * 17 + c4] = weU[(size_t)rows[d * 64 + row] * 16 + c4];
        }
        if (t < 128) {                             // 2 docs x 4 pad rows x 16
            const int d = t >> 6, rem = t & 63;
            const int row = 64 + (rem >> 4), c4 = rem & 15;
            ldsU[d * 1156 + row * 17 + c4] = (uint4){0u, 0u, 0u, 0u};
        }
    }
    __syncthreads();

    float m3[4], m4[4], m5[4];
    conv_g2<12,  0, 62>(lds, Bpack, b3, p, nth, l, m3);
    conv_g2<16, 12, 61>(lds, Bpack, b4, p, nth, l, m4);
    conv_g2<20, 28, 60>(lds, Bpack, b5, p, nth, l, m5);
    __syncthreads();                          // docs dead beyond this point

    float* feats = (float*)lds;               // [2][384] aliases doc buffer
    if ((l >> 4) == 0) {
        const int lm = l & 15;
        #pragma unroll
        for (int k = 0; k < 4; ++k) {
            const int c = nth * 64 + k * 16 + lm;
            feats[p * 384 +   0 + c] = m3[k];
            feats[p * 384 + 128 + c] = m4[k];
            feats[p * 384 + 256 + c] = m5[k];
        }
    }
    __syncthreads();

    // fc epilogue: threads 0..127, each output dim for both docs
    if (t < 128) {
        const float4* wr4 = (const float4*)(fcw + (size_t)t * (3 * CC));
        float a0 = fcb[t], a1 = a0;
        for (int f4 = 0; f4 < 96; ++f4) {
            const float4 wv = wr4[f4];
            const float4 x0 = *(const float4*)&feats[0 * 384 + f4 * 4];
            const float4 x1 = *(const float4*)&feats[1 * 384 + f4 * 4];
            a0 += x0.x * wv.x + x0.y * wv.y + x0.z * wv.z + x0.w * wv.w;
            a1 += x1.x * wv.x + x1.y * wv.y + x1.z * wv.z + x1.w * wv.w;
        }
        out[(size_t)(n0 + 0) * EE + t] = a0;
        out[(size_t)(n0 + 1) * EE + t] = a1;
    }
}

// ---------------------------------------------------------------------------
extern "C" void kernel_launch(void* const* d_in, const int* in_sizes, int n_in,
                              void* d_out, int out_size, void* d_ws, size_t ws_size,
                              hipStream_t stream)
{
    const int*   word2news     = (const int*)d_in[0];
    const int*   word2news_len = (const int*)d_in[1];
    const int*   news_words    = (const int*)d_in[2];
    const float* table         = (const float*)d_in[3];
    const float* in_w          = (const float*)d_in[4];
    const float* in_b          = (const float*)d_in[5];
    const float* out_w         = (const float*)d_in[6];
    const float* out_b         = (const float*)d_in[7];
    const float* w3            = (const float*)d_in[8];
    const float* b3            = (const float*)d_in[9];
    const float* w4            = (const float*)d_in[10];
    const float* b4            = (const float*)d_in[11];
    const float* w5            = (const float*)d_in[12];
    const float* b5            = (const float*)d_in[13];
    const float* fcw           = (const float*)d_in[14];
    const float* fcb           = (const float*)d_in[15];

    float* out = (float*)d_out;
    u16* base  = (u16*)d_ws;
    u16* we16  = base;                                   // 5.12 MB
    u16* Bpack = base + 2560000;                         // 0.39 MB
    u16* Kn16  = base + 2756608;                         // 2.10 MB
    u16* Vn16  = base + 3805184;                         // 2.10 MB  (total 9.71 MB)

    pack_weights<<<48, 256, 0, stream>>>(w3, w4, w5, Bpack);
    kv_proj_kernel<<<NN / 8, 256, 0, stream>>>(table, in_w, in_b, Kn16, Vn16);
    word_attn_kernel<<<V_WORDS / WPB, 256, 0, stream>>>(
        word2news, word2news_len, table, in_w, in_b, out_w, out_b,
        Kn16, Vn16, we16);
    news_kernel<<<NN / 2, 256, 0, stream>>>(
        news_words, we16, Bpack, b3, b4, b5, fcw, fcb, out);
}

// Round 16
// 429.765 us; speedup vs baseline: 2.2594x; 1.0503x over previous
//
#include <hip/hip_runtime.h>
#include <math.h>

#define V_WORDS 20000
#define MM 32
#define EE 128
#define HH 4
#define DHH 32
#define NN 8192
#define LL 64
#define CC 128

typedef short bf16x8 __attribute__((ext_vector_type(8)));
typedef float f32x4 __attribute__((ext_vector_type(4)));
typedef unsigned short u16;
typedef unsigned int u32;

__device__ __forceinline__ u16 f2bf(float x) {
    u32 u = __float_as_uint(x);
    u32 r = (u + 0x7FFFu + ((u >> 16) & 1u)) >> 16;
    return (u16)r;
}
__device__ __forceinline__ float bflo(u32 u) { return __uint_as_float(u << 16); }
__device__ __forceinline__ float bfhi(u32 u) { return __uint_as_float(u & 0xFFFF0000u); }

// ---------------------------------------------------------------------------
// Kernel 0: pack conv weights into bf16 MFMA B-fragment order (unchanged).
// ---------------------------------------------------------------------------
__global__ __launch_bounds__(256)
void pack_weights(const float* __restrict__ w3,
                  const float* __restrict__ w4,
                  const float* __restrict__ w5,
                  u16* __restrict__ Bpack)
{
    const int s = blockIdx.x;
    const int t = threadIdx.x;
    const int lane = t & 63;

    const float* src;
    int K, sl;
    if (s < 12)      { src = w3; K = 3; sl = s; }
    else if (s < 28) { src = w4; K = 4; sl = s - 12; }
    else             { src = w5; K = 5; sl = s - 28; }
    const int j  = sl >> 2;
    const int e0 = (sl & 3) * 32;

    for (int nt = (t >> 6); nt < 8; nt += 4) {
        const int c = nt * 16 + (lane & 15);
        const int kb = (lane >> 4) * 8;
        u16 vals[8];
        #pragma unroll
        for (int i = 0; i < 8; ++i) {
            const int e = e0 + kb + i;
            vals[i] = f2bf(src[(c * EE + e) * K + j]);
        }
        u16* dst = Bpack + (((size_t)s * 8 + nt) * 64 + lane) * 8;
        *(bf16x8*)dst = *(const bf16x8*)vals;
    }
}

// ---------------------------------------------------------------------------
// Kernel A: Kn/Vn projections over the 8192 distinct news rows (unchanged).
// ---------------------------------------------------------------------------
__global__ __launch_bounds__(256)
void kv_proj_kernel(const float* __restrict__ table,
                    const float* __restrict__ in_w,
                    const float* __restrict__ in_b,
                    u16* __restrict__ Kn16, u16* __restrict__ Vn16)
{
    const int n0 = blockIdx.x * 8;
    const int t = threadIdx.x;
    __shared__ float tbl[8][EE];
    {
        const int r = t >> 5, q4 = (t & 31) * 4;
        *(float4*)&tbl[r][q4] = *(const float4*)&table[(size_t)(n0 + r) * EE + q4];
    }
    __syncthreads();

    const int sel = t >> 7;
    const int i = t & 127;
    const float* w = in_w + (size_t)(sel + 1) * EE * EE + (size_t)i * EE;
    const float bias = in_b[(sel + 1) * EE + i];

    float acc[8];
    #pragma unroll
    for (int r = 0; r < 8; ++r) acc[r] = bias;
    for (int k = 0; k < EE; k += 4) {
        const float4 wv = *(const float4*)&w[k];
        #pragma unroll
        for (int r = 0; r < 8; ++r) {
            acc[r] += tbl[r][k]     * wv.x + tbl[r][k + 1] * wv.y
                    + tbl[r][k + 2] * wv.z + tbl[r][k + 3] * wv.w;
        }
    }
    u16* dst = sel ? Vn16 : Kn16;
    #pragma unroll
    for (int r = 0; r < 8; ++r) dst[(size_t)(n0 + r) * EE + i] = f2bf(acc[r]);
}

// ---------------------------------------------------------------------------
// Kernel B: per-word attention (unchanged from R15 — demand-bounded loops +
// (256,3); VGPR 56, no spill, ~138 us. Structural plateau: serial phase
// chain over scattered gathers, occupancy no longer the limiter.)
// ---------------------------------------------------------------------------
#define WPB 8
__global__ __launch_bounds__(256, 3)
void word_attn_kernel(const int* __restrict__ word2news,
                      const int* __restrict__ word2news_len,
                      const float* __restrict__ table,
                      const float* __restrict__ in_w,
                      const float* __restrict__ in_b,
                      const float* __restrict__ out_w,
                      const float* __restrict__ out_b,
                      const u16* __restrict__ Kn16,
                      const u16* __restrict__ Vn16,
                      u16* __restrict__ we16)
{
    const int v0 = blockIdx.x * WPB;
    const int t = threadIdx.x;

    __shared__ int   rows[WPB][MM];
    __shared__ int   lenS[WPB];
    __shared__ float q[WPB][EE];
    __shared__ float qh[WPB][EE];
    __shared__ float attn[WPB][HH][MM];
    __shared__ float osh[WPB][EE];

    {
        const int w = t >> 5, m = t & 31;
        rows[w][m] = word2news[(size_t)(v0 + w) * MM + m];
        if (t < WPB) lenS[t] = word2news_len[v0 + t];
    }
    __syncthreads();

    // q = masked mean of table rows (fixed trip, 4-deep pipelined loads)
    {
        const int w = t >> 5, d0 = (t & 31) * 4;
        const int L = lenS[w];
        float4 a = {0.f, 0.f, 0.f, 0.f};
        #pragma unroll 4
        for (int m = 0; m < MM; ++m) {
            const float4 x = *(const float4*)&table[(size_t)rows[w][m] * EE + d0];
            if (m < L) { a.x += x.x; a.y += x.y; a.z += x.z; a.w += x.w; }
        }
        const float inv = (L > 0) ? 1.0f / (float)L : 0.0f;
        a.x *= inv; a.y *= inv; a.z *= inv; a.w *= inv;
        *(float4*)&q[w][d0] = a;
    }
    __syncthreads();

    // qh = q @ wq^T + bq  (bounded 4-deep weight-load window)
    {
        const int g = t >> 7, i = t & 127;
        const float* wr = in_w + (size_t)i * EE;
        float acc[4] = {0.f, 0.f, 0.f, 0.f};
        #pragma unroll 4
        for (int k = 0; k < EE; k += 4) {
            const float4 wv = *(const float4*)&wr[k];
            #pragma unroll
            for (int w4 = 0; w4 < 4; ++w4) {
                const float* qw = q[g * 4 + w4];
                acc[w4] += qw[k] * wv.x + qw[k + 1] * wv.y
                         + qw[k + 2] * wv.z + qw[k + 3] * wv.w;
            }
        }
        const float b = in_b[i];
        #pragma unroll
        for (int w4 = 0; w4 < 4; ++w4) qh[g * 4 + w4][i] = acc[w4] + b;
    }
    __syncthreads();

    // scores (gather Kn rows) + softmax over m; one head at a time so only
    // 4 uint4 of the Kn row are in flight (not the hoisted 16).
    {
        const int w = t >> 5, m = t & 31;
        const int L = lenS[w];
        float s[HH] = {-1e9f, -1e9f, -1e9f, -1e9f};
        if (m < L) {
            const uint4* kr = (const uint4*)(Kn16 + (size_t)rows[w][m] * EE);
            #pragma unroll 1
            for (int h = 0; h < HH; ++h) {
                float a = 0.f;
                #pragma unroll
                for (int k8 = 0; k8 < 4; ++k8) {
                    const uint4 u = kr[h * 4 + k8];
                    const float4 q0 = *(const float4*)&qh[w][h * 32 + k8 * 8];
                    const float4 q1 = *(const float4*)&qh[w][h * 32 + k8 * 8 + 4];
                    a += q0.x * bflo(u.x) + q0.y * bfhi(u.x)
                       + q0.z * bflo(u.y) + q0.w * bfhi(u.y)
                       + q1.x * bflo(u.z) + q1.y * bfhi(u.z)
                       + q1.z * bflo(u.w) + q1.w * bfhi(u.w);
                }
                s[h] = a * 0.17677669529663687f;
            }
        }
        #pragma unroll
        for (int h = 0; h < HH; ++h) {
            float mx = s[h];
            #pragma unroll
            for (int off = 16; off > 0; off >>= 1)
                mx = fmaxf(mx, __shfl_xor(mx, off, 32));
            const float ex = expf(s[h] - mx);      // masked lanes underflow to 0
            float sum = ex;
            #pragma unroll
            for (int off = 16; off > 0; off >>= 1)
                sum += __shfl_xor(sum, off, 32);
            attn[w][h][m] = ex / sum;
        }
    }
    __syncthreads();

    // o = attn-weighted sum of Vn rows (fixed trip; attn==0 for m>=len)
    {
        const int w = t >> 5, d0 = (t & 31) * 4;
        const int h = d0 >> 5;
        float4 a = {0.f, 0.f, 0.f, 0.f};
        #pragma unroll 4
        for (int m = 0; m < MM; ++m) {
            const float aw = attn[w][h][m];
            const u32* vr = (const u32*)(Vn16 + (size_t)rows[w][m] * EE + d0);
            const u32 u0 = vr[0], u1 = vr[1];
            a.x += aw * bflo(u0); a.y += aw * bfhi(u0);
            a.z += aw * bflo(u1); a.w += aw * bfhi(u1);
        }
        *(float4*)&osh[w][d0] = a;
    }
    __syncthreads();

    // out proj + bf16 store (bounded 4-deep weight-load window)
    {
        const int g = t >> 7, i = t & 127;
        const float* wr = out_w + (size_t)i * EE;
        float acc[4] = {0.f, 0.f, 0.f, 0.f};
        #pragma unroll 4
        for (int k = 0; k < EE; k += 4) {
            const float4 wv = *(const float4*)&wr[k];
            #pragma unroll
            for (int w4 = 0; w4 < 4; ++w4) {
                const float* ow = osh[g * 4 + w4];
                acc[w4] += ow[k] * wv.x + ow[k + 1] * wv.y
                         + ow[k + 2] * wv.z + ow[k + 3] * wv.w;
            }
        }
        const float b = out_b[i];
        #pragma unroll
        for (int w4 = 0; w4 < 4; ++w4) {
            const int w = g * 4 + w4;
            we16[(size_t)(v0 + w) * EE + i] =
                (lenS[w] > 0) ? f2bf(acc[w4] + b) : (u16)0;
        }
    }
}

// ---------------------------------------------------------------------------
// Kernel 2 (R16): implicit-GEMM conv, 4 news per 512-thread block.
// 8 waves; wave = (doc p = w>>1 of 4) x (channel-half nth = w&1).
// PER-WAVE SHAPE IDENTICAL TO THE R12/R14 OPTIMUM: acc 4x4 f32x4 (64 AGPR),
// unroll 2 K-loop (64 arch + 64 AGPR measured, zero spill). Only the block
// envelope grows: (512,4) -> cap 128/thread (same), 2 blocks/CU = 16 waves
// = 4 waves/SIMD where the (256,4) config stalled at 3 blocks (12 waves).
// B-traffic per doc also halves (4 docs share each wave-pair's B stream).
// GUARDRAIL: WRITE_SIZE GB-scale => spill; Occupancy ~25% => 1-block
// admission. Either => revert to R14 news config.
// ---------------------------------------------------------------------------
#define DSTRIDE 136              // u16 per doc row (16B-aligned, 68 words)
#define DOCSZ   (68 * DSTRIDE)   // u16 per doc (64 data rows + 4 zero rows)

template<int NSL, int SBASE, int NP>
__device__ __forceinline__ void conv_g2(const u16* __restrict__ lds,
                                        const u16* __restrict__ Bpack,
                                        const float* __restrict__ bk,
                                        int p, int nth, int l,
                                        float (&mxout)[4])
{
    f32x4 acc[4][4];
    #pragma unroll
    for (int mt = 0; mt < 4; ++mt)
        #pragma unroll
        for (int k = 0; k < 4; ++k)
            acc[mt][k] = (f32x4){0.f, 0.f, 0.f, 0.f};

    const int lm = l & 15;
    const int g  = l >> 4;
    const u16* bbase = Bpack + ((size_t)SBASE * 8 + nth * 4) * 512 + l * 8;
    const u16* abase = lds + (size_t)p * DOCSZ;

    #pragma unroll 2
    for (int s = 0; s < NSL; ++s) {
        const int j  = s >> 2;
        const int e0 = (s & 3) * 32;

        bf16x8 b[4];
        #pragma unroll
        for (int k = 0; k < 4; ++k)
            b[k] = *(const bf16x8*)(bbase + s * 4096 + k * 512);

        const u16* arow = abase + (lm + j) * DSTRIDE + e0 + g * 8;
        bf16x8 a[4];
        #pragma unroll
        for (int mt = 0; mt < 4; ++mt)
            a[mt] = *(const bf16x8*)(arow + mt * (16 * DSTRIDE));

        #pragma unroll
        for (int mt = 0; mt < 4; ++mt)
            #pragma unroll
            for (int k = 0; k < 4; ++k)
                acc[mt][k] = __builtin_amdgcn_mfma_f32_16x16x32_bf16(a[mt], b[k], acc[mt][k], 0, 0, 0);
    }

    // epilogue: +bias, relu, masked max over positions, reduce across row-groups
    #pragma unroll
    for (int k = 0; k < 4; ++k) {
        const int c = nth * 64 + k * 16 + lm;
        const float bias = bk[c];
        float mx = 0.0f;                     // relu output >= 0
        #pragma unroll
        for (int mt = 0; mt < 4; ++mt) {
            #pragma unroll
            for (int r = 0; r < 4; ++r) {
                const int pos = 16 * mt + g * 4 + r;
                const float y = fmaxf(acc[mt][k][r] + bias, 0.0f);
                if (pos < NP) mx = fmaxf(mx, y);
            }
        }
        mx = fmaxf(mx, __shfl_xor(mx, 16));
        mx = fmaxf(mx, __shfl_xor(mx, 32));
        mxout[k] = mx;
    }
}

__global__ __launch_bounds__(512, 4)
void news_kernel(const int* __restrict__ news_words,
                 const u16* __restrict__ we16,
                 const u16* __restrict__ Bpack,
                 const float* __restrict__ b3,
                 const float* __restrict__ b4,
                 const float* __restrict__ b5,
                 const float* __restrict__ fcw, const float* __restrict__ fcb,
                 float* __restrict__ out)
{
    const int n0 = blockIdx.x * 4;
    const int t = threadIdx.x;
    const int w = t >> 6, l = t & 63;
    const int p = w >> 1, nth = w & 1;

    __shared__ u16 lds[4 * DOCSZ];           // 73,984 B; feats alias after convs
    __shared__ int rows[4 * LL];

    if (t < 4 * LL) rows[t] = news_words[(size_t)n0 * LL + t];
    __syncthreads();

    // gather 4 docs as uint4 (16B) rows + zero the 4 pad rows per doc.
    // doc row = 16 data uint4 + 1 pad uint4 (stride 17); pads never read.
    {
        const uint4* weU = (const uint4*)we16;     // 16 uint4 per doc row
        uint4* ldsU = (uint4*)lds;                 // doc stride 1156 uint4
        for (int idx = t; idx < 4096; idx += 512) {
            const int d = idx >> 10, rem = idx & 1023;
            const int row = rem >> 4, c4 = rem & 15;
            ldsU[d * 1156 + row * 17 + c4] = weU[(size_t)rows[d * 64 + row] * 16 + c4];
        }
        if (t < 256) {                             // 4 docs x 4 pad rows x 16
            const int d = t >> 6, rem = t & 63;
            const int row = 64 + (rem >> 4), c4 = rem & 15;
            ldsU[d * 1156 + row * 17 + c4] = (uint4){0u, 0u, 0u, 0u};
        }
    }
    __syncthreads();

    float m3[4], m4[4], m5[4];
    conv_g2<12,  0, 62>(lds, Bpack, b3, p, nth, l, m3);
    conv_g2<16, 12, 61>(lds, Bpack, b4, p, nth, l, m4);
    conv_g2<20, 28, 60>(lds, Bpack, b5, p, nth, l, m5);
    __syncthreads();                          // docs dead beyond this point

    float* feats = (float*)lds;               // [4][384] aliases doc buffer
    if ((l >> 4) == 0) {
        const int lm = l & 15;
        #pragma unroll
        for (int k = 0; k < 4; ++k) {
            const int c = nth * 64 + k * 16 + lm;
            feats[p * 384 +   0 + c] = m3[k];
            feats[p * 384 + 128 + c] = m4[k];
            feats[p * 384 + 256 + c] = m5[k];
        }
    }
    __syncthreads();

    // fc epilogue: threads 0..127, each output dim for all 4 docs
    if (t < 128) {
        const float4* wr4 = (const float4*)(fcw + (size_t)t * (3 * CC));
        float a0 = fcb[t], a1 = a0, a2 = a0, a3 = a0;
        for (int f4 = 0; f4 < 96; ++f4) {
            const float4 wv = wr4[f4];
            const float4 x0 = *(const float4*)&feats[0 * 384 + f4 * 4];
            const float4 x1 = *(const float4*)&feats[1 * 384 + f4 * 4];
            const float4 x2 = *(const float4*)&feats[2 * 384 + f4 * 4];
            const float4 x3 = *(const float4*)&feats[3 * 384 + f4 * 4];
            a0 += x0.x * wv.x + x0.y * wv.y + x0.z * wv.z + x0.w * wv.w;
            a1 += x1.x * wv.x + x1.y * wv.y + x1.z * wv.z + x1.w * wv.w;
            a2 += x2.x * wv.x + x2.y * wv.y + x2.z * wv.z + x2.w * wv.w;
            a3 += x3.x * wv.x + x3.y * wv.y + x3.z * wv.z + x3.w * wv.w;
        }
        out[(size_t)(n0 + 0) * EE + t] = a0;
        out[(size_t)(n0 + 1) * EE + t] = a1;
        out[(size_t)(n0 + 2) * EE + t] = a2;
        out[(size_t)(n0 + 3) * EE + t] = a3;
    }
}

// ---------------------------------------------------------------------------
extern "C" void kernel_launch(void* const* d_in, const int* in_sizes, int n_in,
                              void* d_out, int out_size, void* d_ws, size_t ws_size,
                              hipStream_t stream)
{
    const int*   word2news     = (const int*)d_in[0];
    const int*   word2news_len = (const int*)d_in[1];
    const int*   news_words    = (const int*)d_in[2];
    const float* table         = (const float*)d_in[3];
    const float* in_w          = (const float*)d_in[4];
    const float* in_b          = (const float*)d_in[5];
    const float* out_w         = (const float*)d_in[6];
    const float* out_b         = (const float*)d_in[7];
    const float* w3            = (const float*)d_in[8];
    const float* b3            = (const float*)d_in[9];
    const float* w4            = (const float*)d_in[10];
    const float* b4            = (const float*)d_in[11];
    const float* w5            = (const float*)d_in[12];
    const float* b5            = (const float*)d_in[13];
    const float* fcw           = (const float*)d_in[14];
    const float* fcb           = (const float*)d_in[15];

    float* out = (float*)d_out;
    u16* base  = (u16*)d_ws;
    u16* we16  = base;                                   // 5.12 MB
    u16* Bpack = base + 2560000;                         // 0.39 MB
    u16* Kn16  = base + 2756608;                         // 2.10 MB
    u16* Vn16  = base + 3805184;                         // 2.10 MB  (total 9.71 MB)

    pack_weights<<<48, 256, 0, stream>>>(w3, w4, w5, Bpack);
    kv_proj_kernel<<<NN / 8, 256, 0, stream>>>(table, in_w, in_b, Kn16, Vn16);
    word_attn_kernel<<<V_WORDS / WPB, 256, 0, stream>>>(
        word2news, word2news_len, table, in_w, in_b, out_w, out_b,
        Kn16, Vn16, we16);
    news_kernel<<<NN / 4, 512, 0, stream>>>(
        news_words, we16, Bpack, b3, b4, b5, fcw, fcb, out);
}